// Round 3
// baseline (20.501 us; speedup 1.0000x reference)
//
#include <hip/hip_runtime.h>

#define IN_DIM   2048
#define OUT_DIM  16384
#define NT       256
#define ROWS     2
#define EPS      1e-12f

// out[b][j] = -scale * rnorm_b * WHT2048(x[b])[j & 2047] + bias[j]
// FWHT stages commute, so passes are scheduled bits{8-10},{3-5},{6-7},{0-2}:
// the load is strided (8 coalesced b32/thread) and the FINAL layout is
// 8 consecutive elements per thread -> direct b128 stores, no extra LDS pass.
// swz keeps every LDS boundary at <=2-way bank aliasing (free per m136).

__device__ __forceinline__ int swz(int e) { return e ^ (((e >> 6) & 7) << 3); }

#define BFLY(m)                                                   \
    _Pragma("unroll")                                             \
    for (int k = 0; k < 8; ++k)                                   \
        if (!(k & (m))) {                                         \
            const float a_ = v[k], b_ = v[k | (m)];               \
            v[k]       = a_ + b_;                                 \
            v[k | (m)] = a_ - b_;                                 \
        }

__global__ __launch_bounds__(NT, 2) void had_fwht_kernel(
    const float* __restrict__ x,
    const float* __restrict__ scale,
    const float* __restrict__ bias,
    float* __restrict__ out)
{
    __shared__ float sA[ROWS][IN_DIM];     // double-buffered shuffle space
    __shared__ float red[ROWS][NT / 64];

    const int g  = blockIdx.x;
    const int t  = threadIdx.x;
    const int wv = t >> 6;

    const float negscale = -scale[0];

    // ---- hoist bias into registers: bj[2*tile+h] = bias4[tile*512 + 2t + h]
    const float4* bias4 = (const float4*)bias;
    float4 bj[16];
#pragma unroll
    for (int i = 0; i < 16; ++i)
        bj[i] = bias4[(i >> 1) * 512 + 2 * t + (i & 1)];

    // ---- prefetch row 0 in L0 layout: e = (k<<8) | t  (coalesced b32 x8)
    float p[8];
    {
        const float* xr = x + (size_t)(g * ROWS) * IN_DIM;
#pragma unroll
        for (int k = 0; k < 8; ++k) p[k] = xr[(k << 8) + t];
    }

#pragma unroll
    for (int rr = 0; rr < ROWS; ++rr) {
        const int row = g * ROWS + rr;
        float v[8];
#pragma unroll
        for (int k = 0; k < 8; ++k) v[k] = p[k];

        // ---- sum of squares: wave shuffle, cross-wave via red[rr]
        float local = 0.f;
#pragma unroll
        for (int k = 0; k < 8; ++k) local = fmaf(v[k], v[k], local);
#pragma unroll
        for (int off = 32; off > 0; off >>= 1)
            local += __shfl_down(local, off, 64);
        if ((t & 63) == 0) red[rr][wv] = local;

        // ---- pass 1: bits 8..10 (d = 256,512,1024)
        BFLY(1) BFLY(2) BFLY(4)
#pragma unroll
        for (int k = 0; k < 8; ++k) sA[rr][swz((k << 8) | t)] = v[k];

        // ---- prefetch next row BEFORE the barrier: loads fly under passes 2-4
        // (waiting for them later only needs vmcnt<=16: stores are newer)
        if (rr + 1 < ROWS) {
            const float* xn = x + (size_t)(row + 1) * IN_DIM;
#pragma unroll
            for (int k = 0; k < 8; ++k) p[k] = xn[(k << 8) + t];
        }
        __syncthreads();

        // ---- pass 2: bits 3..5; L1: e = (t>>3)<<6 | k<<3 | (t&7)
        const int b1 = ((t >> 3) << 6) | (t & 7);
#pragma unroll
        for (int k = 0; k < 8; ++k) v[k] = sA[rr][swz(b1 | (k << 3))];
        BFLY(1) BFLY(2) BFLY(4)
#pragma unroll
        for (int k = 0; k < 8; ++k) sA[rr][swz(b1 | (k << 3))] = v[k];
        __syncthreads();

        const float sumsq = red[rr][0] + red[rr][1] + red[rr][2] + red[rr][3];
        const float c = negscale * rsqrtf(fmaxf(sumsq, EPS));

        // ---- pass 3: bits 6..7; L2: e = (k>>2)<<10 | (t>>6)<<8 | (k&3)<<6 | (t&63)
        const int b2 = ((t >> 6) << 8) | (t & 63);
#pragma unroll
        for (int k = 0; k < 8; ++k)
            v[k] = sA[rr][swz(((k >> 2) << 10) | ((k & 3) << 6) | b2)];
        BFLY(1) BFLY(2)                        // k[2] (=bit 10) passive: done in pass 1
#pragma unroll
        for (int k = 0; k < 8; ++k)
            sA[rr][swz(((k >> 2) << 10) | ((k & 3) << 6) | b2)] = v[k];
        __syncthreads();

        // ---- pass 4: bits 0..2; L3: e = t<<3 | k (swz preserves low 3 bits)
        {
            const int base = swz(t << 3);      // 32B-aligned
            const float4 lo = *(const float4*)&sA[rr][base];
            const float4 hi = *(const float4*)&sA[rr][base + 4];
            v[0] = lo.x; v[1] = lo.y; v[2] = lo.z; v[3] = lo.w;
            v[4] = hi.x; v[5] = hi.y; v[6] = hi.z; v[7] = hi.w;
        }
        BFLY(1) BFLY(2) BFLY(4)

        // ---- stores: out[row][tile*2048 + 8t + k], pure b128 stores, no loads
        float4* orow = (float4*)(out + (size_t)row * OUT_DIM);
#pragma unroll
        for (int tile = 0; tile < 8; ++tile) {
            float4 o0, o1;
            o0.x = fmaf(c, v[0], bj[2 * tile].x);
            o0.y = fmaf(c, v[1], bj[2 * tile].y);
            o0.z = fmaf(c, v[2], bj[2 * tile].z);
            o0.w = fmaf(c, v[3], bj[2 * tile].w);
            o1.x = fmaf(c, v[4], bj[2 * tile + 1].x);
            o1.y = fmaf(c, v[5], bj[2 * tile + 1].y);
            o1.z = fmaf(c, v[6], bj[2 * tile + 1].z);
            o1.w = fmaf(c, v[7], bj[2 * tile + 1].w);
            orow[tile * 512 + 2 * t]     = o0;
            orow[tile * 512 + 2 * t + 1] = o1;
        }
    }
}

extern "C" void kernel_launch(void* const* d_in, const int* in_sizes, int n_in,
                              void* d_out, int out_size, void* d_ws, size_t ws_size,
                              hipStream_t stream) {
    const float* x     = (const float*)d_in[0];
    const float* scale = (const float*)d_in[1];
    const float* bias  = (const float*)d_in[2];
    // d_in[3] (dense hadamard) unused: structure exploited in-kernel.
    float* out = (float*)d_out;

    const int batch = in_sizes[0] / IN_DIM;   // 1024
    had_fwht_kernel<<<batch / ROWS, NT, 0, stream>>>(x, scale, bias, out);
}